// Round 11
// baseline (332.928 us; speedup 1.0000x reference)
//
#include <hip/hip_runtime.h>
#include <stdint.h>

#define N_NODES 50000
#define N_EDGES 800000
#define NFEAT 512
#define NHID 128
#define NCLASS 40
#define NBLK 3125   // 800000 / 256 edge blocks
#define NBUCK 196   // ceil(50000/256) coarse dst buckets

typedef __attribute__((ext_vector_type(8))) __bf16 bf16x8;
typedef __attribute__((ext_vector_type(4))) float f32x4;
typedef _Float16 h2 __attribute__((ext_vector_type(2)));
typedef _Float16 f16x8 __attribute__((ext_vector_type(8)));

__device__ __forceinline__ uint16_t f2b(float f) {
  uint32_t x = __float_as_uint(f);
  uint32_t r = (x + 0x7fffu + ((x >> 16) & 1u)) >> 16;
  return (uint16_t)r;
}
__device__ __forceinline__ uint16_t f2h_bits(float f) {
  return __builtin_bit_cast(uint16_t, (_Float16)f);
}
__device__ __forceinline__ h2 cvt_pk(float a, float b) {
  return __builtin_bit_cast(h2, __builtin_amdgcn_cvt_pkrtz(a, b));
}

// ---------------- merged prologue: prep WT1(f16)/WT2(bf16) | p1 coarse hist ----------------
// blocks [0,512): WT1 | [512,640): WT2 | [640,3765): p1 (LDS atomics only)
__global__ void k_pre3(const float* __restrict__ W1, const float* __restrict__ Wr1,
                       const float* __restrict__ W2, const float* __restrict__ Wr2,
                       uint16_t* __restrict__ WT1h, uint16_t* __restrict__ WT2,
                       const int* __restrict__ dst, int* __restrict__ bc) {
  int b = blockIdx.x, t = threadIdx.x;
  if (b < 512) {
    int idx = b * 256 + t;  // 131072
    int n = idx >> 9, k = idx & 511;
    float v = (n < 128) ? W1[(size_t)k * 128 + n] : Wr1[(size_t)k * 128 + (n - 128)];
    WT1h[idx] = f2h_bits(v);
  } else if (b < 640) {
    int j = (b - 512) * 256 + t;  // 32768
    int n = j >> 8, k = j & 255;
    float v = 0.f;
    if (n < 40) v = W2[(size_t)k * 40 + n];
    else if (n < 80) v = Wr2[(size_t)k * 40 + (n - 40)];
    WT2[j] = f2b(v);
  } else {
    __shared__ int hist[NBUCK];
    int eb = b - 640;  // 0..3124
    if (t < NBUCK) hist[t] = 0;
    __syncthreads();
    int d = dst[eb * 256 + t];
    atomicAdd(&hist[d >> 8], 1);
    __syncthreads();
    if (t < NBUCK) bc[eb * NBUCK + t] = hist[t];
  }
}

// ---------------- P2: per-bucket scan over blocks: bc[b][k] -> bc2[k][b] excl, totals ----------------
__global__ void k_p2(const int* __restrict__ bc, int* __restrict__ bc2,
                     int* __restrict__ bucketTotal) {
  __shared__ int part[256];
  int k = blockIdx.x, t = threadIdx.x;
  int vals[13];
  int s = 0;
  int base = t * 13;
#pragma unroll
  for (int i = 0; i < 13; i++) {
    int idx = base + i;
    int v = (idx < NBLK) ? bc[idx * NBUCK + k] : 0;
    vals[i] = v;
    s += v;
  }
  part[t] = s;
  __syncthreads();
  for (int o = 1; o < 256; o <<= 1) {
    int v = (t >= o) ? part[t - o] : 0;
    __syncthreads();
    part[t] += v;
    __syncthreads();
  }
  int run = (t == 0) ? 0 : part[t - 1];
#pragma unroll
  for (int i = 0; i < 13; i++) {
    int idx = base + i;
    if (idx < NBLK) {
      bc2[k * NBLK + idx] = run;
      run += vals[i];
    }
  }
  if (t == 255) bucketTotal[k] = part[255];
}

// ---------------- P4: coarse scatter, inline bucket-base scan, LDS cursors ----------------
__global__ void k_p4(const int* __restrict__ src, const int* __restrict__ dst,
                     const float* __restrict__ val, const int* __restrict__ bc2,
                     const int* __restrict__ bucketTotal, int2* __restrict__ esc) {
  __shared__ int sc[256];
  __shared__ int start[NBUCK];
  __shared__ int cur[NBUCK];
  int b = blockIdx.x, t = threadIdx.x;
  sc[t] = (t < NBUCK) ? bucketTotal[t] : 0;
  __syncthreads();
  for (int o = 1; o < 256; o <<= 1) {
    int v = (t >= o) ? sc[t - o] : 0;
    __syncthreads();
    sc[t] += v;
    __syncthreads();
  }
  if (t < NBUCK) {
    start[t] = ((t == 0) ? 0 : sc[t - 1]) + bc2[t * NBLK + b];
    cur[t] = 0;
  }
  __syncthreads();
  int e = b * 256 + t;
  int d = dst[e];
  int k = d >> 8;
  int r = atomicAdd(&cur[k], 1);  // LDS atomic
  esc[start[k] + r] = make_int2(src[e] | ((d & 255) << 16), __float_as_int(val[e]));
}

// ---------------- P5: per-bucket exact sort (inline bucket-base scan) -> es + offs ----------------
__global__ void k_p5(const int2* __restrict__ esc, const int* __restrict__ bucketTotal,
                     int2* __restrict__ es, int* __restrict__ offs) {
  __shared__ int bsc[256];
  __shared__ int hist[256];
  __shared__ int sc[256];
  __shared__ int cur[256];
  int k = blockIdx.x, t = threadIdx.x;
  bsc[t] = (t < NBUCK) ? bucketTotal[t] : 0;
  __syncthreads();
  for (int o = 1; o < 256; o <<= 1) {
    int v = (t >= o) ? bsc[t - o] : 0;
    __syncthreads();
    bsc[t] += v;
    __syncthreads();
  }
  int base = (k == 0) ? 0 : bsc[k - 1];
  int n = bsc[k] - base;
  hist[t] = 0;
  __syncthreads();
  for (int i = t; i < n; i += 256) atomicAdd(&hist[esc[base + i].x >> 16], 1);
  __syncthreads();
  sc[t] = hist[t];
  __syncthreads();
  for (int o = 1; o < 256; o <<= 1) {
    int v = (t >= o) ? sc[t - o] : 0;
    __syncthreads();
    sc[t] += v;
    __syncthreads();
  }
  int excl = (t == 0) ? 0 : sc[t - 1];
  int node = k * 256 + t;
  if (node <= N_NODES) offs[node] = base + excl;
  cur[t] = excl;
  __syncthreads();
  for (int i = t; i < n; i += 256) {
    int2 e = esc[base + i];
    int l = e.x >> 16;
    int r = atomicAdd(&cur[l], 1);  // LDS atomic
    es[base + r] = make_int2(e.x & 0xFFFF, e.y);
  }
}

// ---------------- fused cast+GEMM1: x(fp32) @ WT1h^T, f16 MFMA, register-staged A ----------------
// A path: per-lane dwordx4 loads + v_cvt_pkrtz (no LDS). B path: proven global_load_lds.
// Same 2-barrier m97 structure and verified C/D-layout epilogue.
__global__ __launch_bounds__(256, 2) void k_gemm1f(
    const float* __restrict__ x, const uint16_t* __restrict__ BTh, int M,
    _Float16* __restrict__ S1h, uint16_t* __restrict__ h, const float* __restrict__ br1) {
  __shared__ uint16_t Bl[128 * 64];
  const int tid = threadIdx.x;
  const int w = tid >> 6, lane = tid & 63;
  const int wm = w >> 1, wn = w & 1;
  const int m0 = blockIdx.x * 128;
  const int n0 = blockIdx.y * 128;
  const int quad = lane >> 4;

  f32x4 acc[4][4];
#pragma unroll
  for (int t = 0; t < 4; t++)
#pragma unroll
    for (int u = 0; u < 4; u++) acc[t][u] = (f32x4)0.f;

  const int lrow = lane >> 3;
  const int lcol = lane & 7;

  // A fragment row pointers (clamped; stores are guarded)
  const float* ap[4];
#pragma unroll
  for (int t = 0; t < 4; t++) {
    int r = m0 + wm * 64 + t * 16 + (lane & 15);
    if (r >= M) r = M - 1;
    ap[t] = x + (size_t)r * NFEAT + quad * 8;
  }

  for (int kb = 0; kb < 8; ++kb) {
    __syncthreads();  // Bl reuse guard (prior MFMA reads done)
    const int k0 = kb * 64;
#pragma unroll
    for (int i = 0; i < 4; i++) {
      int rr = (w * 4 + i) * 8 + lrow;
      const uint16_t* gB = BTh + (size_t)(n0 + rr) * NFEAT + k0 + lcol * 8;
      __builtin_amdgcn_global_load_lds(
          (const __attribute__((address_space(1))) void*)gB,
          (__attribute__((address_space(3))) void*)&Bl[(w * 4 + i) * 512], 16, 0, 0);
    }
    // A: registers only, overlaps B DMA
    f16x8 av[4][2];
#pragma unroll
    for (int t = 0; t < 4; t++) {
#pragma unroll
      for (int s = 0; s < 2; s++) {
        const float* p = ap[t] + k0 + s * 32;
        float4 f0 = *(const float4*)p;
        float4 f1 = *(const float4*)(p + 4);
        union { h2 hh[4]; f16x8 v; } u;
        u.hh[0] = cvt_pk(f0.x, f0.y);
        u.hh[1] = cvt_pk(f0.z, f0.w);
        u.hh[2] = cvt_pk(f1.x, f1.y);
        u.hh[3] = cvt_pk(f1.z, f1.w);
        av[t][s] = u.v;
      }
    }
    __syncthreads();  // drains B DMA (compiler emits vmcnt(0))
#pragma unroll
    for (int s = 0; s < 2; s++) {
      f16x8 bv[4];
#pragma unroll
      for (int u = 0; u < 4; u++)
        bv[u] = *(const f16x8*)&Bl[(wn * 64 + u * 16 + (lane & 15)) * 64 + s * 32 + quad * 8];
#pragma unroll
      for (int t = 0; t < 4; t++)
#pragma unroll
        for (int u = 0; u < 4; u++)
          acc[t][u] = __builtin_amdgcn_mfma_f32_16x16x32_f16(av[t][s], bv[u], acc[t][u], 0, 0, 0);
    }
  }

  const int cl = lane & 15, rq = lane >> 4;
#pragma unroll
  for (int t = 0; t < 4; t++) {
#pragma unroll
    for (int u = 0; u < 4; u++) {
#pragma unroll
      for (int r = 0; r < 4; r++) {
        int m = m0 + wm * 64 + t * 16 + rq * 4 + r;
        int n = n0 + wn * 64 + u * 16 + cl;
        if (m >= M) continue;
        float v = acc[t][u][r];
        if (n < 128)
          S1h[(size_t)m * 128 + n] = (_Float16)v;  // x@W1 (b1 added post-spmm)
        else
          h[(size_t)m * 256 + n] = f2b(v + br1[n - 128]);  // h right = x@Wr1+br1
      }
    }
  }
}

// ---------------- GEMM2: h(bf16) @ WT2^T, 128x128 tile, f16 S2 + padded epilogue (proven) ----------------
__global__ __launch_bounds__(256, 2) void k_gemm2(
    const uint16_t* __restrict__ A, const uint16_t* __restrict__ BT, int M,
    _Float16* __restrict__ S2h, float* __restrict__ oacc,
    const float* __restrict__ b2, const float* __restrict__ br2) {
  __shared__ uint16_t Al[128 * 64];
  __shared__ uint16_t Bl[128 * 64];
  const int tid = threadIdx.x;
  const int w = tid >> 6, lane = tid & 63;
  const int wm = w >> 1, wn = w & 1;
  const int m0 = blockIdx.x * 128;
  const int K = 256;

  f32x4 acc[4][4];
#pragma unroll
  for (int t = 0; t < 4; t++)
#pragma unroll
    for (int u = 0; u < 4; u++) acc[t][u] = (f32x4)0.f;

  const int lrow = lane >> 3;
  const int lcol = lane & 7;

  for (int kb = 0; kb < K / 64; ++kb) {
    __syncthreads();
    const int k0 = kb * 64;
#pragma unroll
    for (int i = 0; i < 4; i++) {
      int rr = (w * 4 + i) * 8 + lrow;
      int ra = m0 + rr;
      if (ra >= M) ra = M - 1;
      const uint16_t* gA = A + (size_t)ra * K + k0 + lcol * 8;
      __builtin_amdgcn_global_load_lds(
          (const __attribute__((address_space(1))) void*)gA,
          (__attribute__((address_space(3))) void*)&Al[(w * 4 + i) * 512], 16, 0, 0);
      const uint16_t* gB = BT + (size_t)rr * K + k0 + lcol * 8;
      __builtin_amdgcn_global_load_lds(
          (const __attribute__((address_space(1))) void*)gB,
          (__attribute__((address_space(3))) void*)&Bl[(w * 4 + i) * 512], 16, 0, 0);
    }
    __syncthreads();
#pragma unroll
    for (int s = 0; s < 2; s++) {
      bf16x8 av[4], bv[4];
#pragma unroll
      for (int t = 0; t < 4; t++)
        av[t] = *(const bf16x8*)&Al[(wm * 64 + t * 16 + (lane & 15)) * 64 + s * 32 + (lane >> 4) * 8];
#pragma unroll
      for (int u = 0; u < 4; u++)
        bv[u] = *(const bf16x8*)&Bl[(wn * 64 + u * 16 + (lane & 15)) * 64 + s * 32 + (lane >> 4) * 8];
#pragma unroll
      for (int t = 0; t < 4; t++)
#pragma unroll
        for (int u = 0; u < 4; u++)
          acc[t][u] = __builtin_amdgcn_mfma_f32_16x16x32_bf16(av[t], bv[u], acc[t][u], 0, 0, 0);
    }
  }

  const int cl = lane & 15, rq = lane >> 4;
#pragma unroll
  for (int t = 0; t < 4; t++) {
#pragma unroll
    for (int u = 0; u < 4; u++) {
#pragma unroll
      for (int r = 0; r < 4; r++) {
        int m = m0 + wm * 64 + t * 16 + rq * 4 + r;
        int n = wn * 64 + u * 16 + cl;
        if (m >= M) continue;
        float v = acc[t][u][r];
        if (n < 40) S2h[(size_t)m * 64 + n] = (_Float16)v;
        else if (n < 64) S2h[(size_t)m * 64 + n] = (_Float16)0.f;
        if (n >= 40 && n < 80) oacc[(size_t)m * 64 + (n - 40)] = v + b2[n - 40] + br2[n - 40];
        else if (n >= 80 && n < 104) oacc[(size_t)m * 64 + (n - 40)] = 0.f;
      }
    }
  }
}

// ---------------- SpMM1 via CSR: wave/node, 8 edges/iter, f16 packed (proven) ----------------
__global__ void k_spmm1_csr(const int* __restrict__ offs, const int2* __restrict__ es,
                            const _Float16* __restrict__ S1h, const float* __restrict__ b1,
                            uint16_t* __restrict__ h) {
  int node = blockIdx.x * 4 + (threadIdx.x >> 6);
  if (node >= N_NODES) return;
  int lane = threadIdx.x & 63;
  int eg = lane >> 4;  // 0..3 edge slot
  int fg = lane & 15;  // 0..15 feat group (8 feats)
  int beg = offs[node], end = offs[node + 1];
  h2 acc[4];
#pragma unroll
  for (int j = 0; j < 4; j++) acc[j] = (h2)(_Float16)0.f;
  for (int p = beg; p < end; p += 8) {
    int pa = p + eg, pb = p + 4 + eg;
    bool oka = pa < end, okb = pb < end;
    int2 ea = es[oka ? pa : beg];
    int2 eb = es[okb ? pb : beg];
    float va = oka ? __int_as_float(ea.y) : 0.f;
    float vb = okb ? __int_as_float(eb.y) : 0.f;
    _Float16 vah = (_Float16)va, vbh = (_Float16)vb;
    h2 vva = {vah, vah}, vvb = {vbh, vbh};
    uint4 ga = *(const uint4*)(S1h + (size_t)ea.x * 128 + fg * 8);
    uint4 gb = *(const uint4*)(S1h + (size_t)eb.x * 128 + fg * 8);
    h2* ha = (h2*)&ga;
    h2* hb = (h2*)&gb;
#pragma unroll
    for (int j = 0; j < 4; j++) {
      acc[j] = vva * ha[j] + acc[j];
      acc[j] = vvb * hb[j] + acc[j];
    }
  }
#pragma unroll
  for (int j = 0; j < 4; j++) {
    int b16 = __shfl_xor(__builtin_bit_cast(int, acc[j]), 16, 64);
    acc[j] = acc[j] + __builtin_bit_cast(h2, b16);
    int b32 = __shfl_xor(__builtin_bit_cast(int, acc[j]), 32, 64);
    acc[j] = acc[j] + __builtin_bit_cast(h2, b32);
  }
  if (eg == 0) {
    const float4* bp = (const float4*)(b1 + fg * 8);
    float4 ba = bp[0], bb = bp[1];
    float r0 = (float)acc[0][0] + ba.x, r1 = (float)acc[0][1] + ba.y;
    float r2 = (float)acc[1][0] + ba.z, r3 = (float)acc[1][1] + ba.w;
    float r4 = (float)acc[2][0] + bb.x, r5 = (float)acc[2][1] + bb.y;
    float r6 = (float)acc[3][0] + bb.z, r7 = (float)acc[3][1] + bb.w;
    union { uint16_t u[8]; uint4 v; } o;
    o.u[0] = f2b(r0 > 0.f ? r0 : 0.f); o.u[1] = f2b(r1 > 0.f ? r1 : 0.f);
    o.u[2] = f2b(r2 > 0.f ? r2 : 0.f); o.u[3] = f2b(r3 > 0.f ? r3 : 0.f);
    o.u[4] = f2b(r4 > 0.f ? r4 : 0.f); o.u[5] = f2b(r5 > 0.f ? r5 : 0.f);
    o.u[6] = f2b(r6 > 0.f ? r6 : 0.f); o.u[7] = f2b(r7 > 0.f ? r7 : 0.f);
    *(uint4*)(h + (size_t)node * 256 + fg * 8) = o.v;
  }
}

// ---------------- SpMM2 via CSR + log_softmax: wave/node, 16 edges/iter (proven) ----------------
__global__ void k_spmm2_lsm(const int* __restrict__ offs, const int2* __restrict__ es,
                            const _Float16* __restrict__ S2h, const float* __restrict__ oacc,
                            float* __restrict__ out) {
  int node = blockIdx.x * 4 + (threadIdx.x >> 6);
  if (node >= N_NODES) return;
  int lane = threadIdx.x & 63;
  int eg = lane >> 3;  // 0..7 edge slot
  int fg = lane & 7;   // 0..7 feat group (8 feats of 64-padded row)
  int beg = offs[node], end = offs[node + 1];
  h2 acc[4];
#pragma unroll
  for (int j = 0; j < 4; j++) acc[j] = (h2)(_Float16)0.f;
  for (int p = beg; p < end; p += 16) {
    int pa = p + eg, pb = p + 8 + eg;
    bool oka = pa < end, okb = pb < end;
    int2 ea = es[oka ? pa : beg];
    int2 eb = es[okb ? pb : beg];
    float va = oka ? __int_as_float(ea.y) : 0.f;
    float vb = okb ? __int_as_float(eb.y) : 0.f;
    _Float16 vah = (_Float16)va, vbh = (_Float16)vb;
    h2 vva = {vah, vah}, vvb = {vbh, vbh};
    uint4 ga = *(const uint4*)(S2h + (size_t)ea.x * 64 + fg * 8);
    uint4 gb = *(const uint4*)(S2h + (size_t)eb.x * 64 + fg * 8);
    h2* ha = (h2*)&ga;
    h2* hb = (h2*)&gb;
#pragma unroll
    for (int j = 0; j < 4; j++) {
      acc[j] = vva * ha[j] + acc[j];
      acc[j] = vvb * hb[j] + acc[j];
    }
  }
#pragma unroll
  for (int j = 0; j < 4; j++) {
    int b8 = __shfl_xor(__builtin_bit_cast(int, acc[j]), 8, 64);
    acc[j] = acc[j] + __builtin_bit_cast(h2, b8);
    int b16 = __shfl_xor(__builtin_bit_cast(int, acc[j]), 16, 64);
    acc[j] = acc[j] + __builtin_bit_cast(h2, b16);
    int b32 = __shfl_xor(__builtin_bit_cast(int, acc[j]), 32, 64);
    acc[j] = acc[j] + __builtin_bit_cast(h2, b32);
  }
  const float4* op = (const float4*)(oacc + (size_t)node * 64 + fg * 8);
  float4 o0 = op[0], o1 = op[1];
  float v0 = (float)acc[0][0] + o0.x, v1 = (float)acc[0][1] + o0.y;
  float v2 = (float)acc[1][0] + o0.z, v3 = (float)acc[1][1] + o0.w;
  float v4 = (float)acc[2][0] + o1.x, v5 = (float)acc[2][1] + o1.y;
  float v6 = (float)acc[3][0] + o1.z, v7 = (float)acc[3][1] + o1.w;
  bool valid = fg < 5;  // feats 0..39
  float m01 = v0 > v1 ? v0 : v1, m23 = v2 > v3 ? v2 : v3;
  float m45 = v4 > v5 ? v4 : v5, m67 = v6 > v7 ? v6 : v7;
  float ml = m01 > m23 ? m01 : m23;
  float mh = m45 > m67 ? m45 : m67;
  float mv = ml > mh ? ml : mh;
  mv = valid ? mv : -1e30f;
#pragma unroll
  for (int o = 1; o <= 4; o <<= 1) {
    float t = __shfl_xor(mv, o, 64);
    mv = mv > t ? mv : t;
  }
  float se = 0.f;
  if (valid)
    se = __expf(v0 - mv) + __expf(v1 - mv) + __expf(v2 - mv) + __expf(v3 - mv) +
         __expf(v4 - mv) + __expf(v5 - mv) + __expf(v6 - mv) + __expf(v7 - mv);
#pragma unroll
  for (int o = 1; o <= 4; o <<= 1) se += __shfl_xor(se, o, 64);
  if (eg == 0 && valid) {
    float ls = mv + __logf(se);
    float4 r0 = make_float4(v0 - ls, v1 - ls, v2 - ls, v3 - ls);
    float4 r1 = make_float4(v4 - ls, v5 - ls, v6 - ls, v7 - ls);
    float4* wp = (float4*)(out + (size_t)node * 40 + fg * 8);
    wp[0] = r0;
    wp[1] = r1;
  }
}

extern "C" void kernel_launch(void* const* d_in, const int* in_sizes, int n_in,
                              void* d_out, int out_size, void* d_ws, size_t ws_size,
                              hipStream_t stream) {
  const float* x = (const float*)d_in[0];
  const int* esrc = (const int*)d_in[1];
  const int* edst = (const int*)d_in[2];
  const float* eval = (const float*)d_in[3];
  const float* W1 = (const float*)d_in[4];
  const float* b1 = (const float*)d_in[5];
  const float* Wr1 = (const float*)d_in[6];
  const float* br1 = (const float*)d_in[7];
  const float* W2 = (const float*)d_in[8];
  const float* b2 = (const float*)d_in[9];
  const float* Wr2 = (const float*)d_in[10];
  const float* br2 = (const float*)d_in[11];
  float* out = (float*)d_out;

  char* ws = (char*)d_ws;
  _Float16* S1h  = (_Float16*)(ws);              // 12,800,000
  uint16_t* h    = (uint16_t*)(ws + 12800000);   // 25,600,000
  uint16_t* WT1h = (uint16_t*)(ws + 38400000);   //    262,144 (f16)
  uint16_t* WT2  = (uint16_t*)(ws + 38662144);   //     65,536 (bf16)
  _Float16* S2h  = (_Float16*)(ws + 38727680);   //  6,400,000 (64-padded)
  float*    oacc = (float*)(ws + 45127680);      // 12,800,000 (64-padded)
  int*      offs = (int*)(ws + 57927680);        //    200,016 (padded)
  int2*     es   = (int2*)(ws + 58127696);       //  6,400,000
  int2*     esc  = (int2*)(ws + 64527696);       //  6,400,000
  int*      bc   = (int*)(ws + 70927696);        //  2,450,000 ([block][bucket])
  int*      bc2  = (int*)(ws + 73377696);        //  2,450,000 ([bucket][block])
  int*      bucketTotal = (int*)(ws + 75827696); //        784  (total ~75.8 MB)

  k_pre3<<<3765, 256, 0, stream>>>(W1, Wr1, W2, Wr2, WT1h, WT2, edst, bc);
  k_p2<<<NBUCK, 256, 0, stream>>>(bc, bc2, bucketTotal);
  k_p4<<<NBLK, 256, 0, stream>>>(esrc, edst, eval, bc2, bucketTotal, esc);
  k_p5<<<NBUCK, 256, 0, stream>>>(esc, bucketTotal, es, offs);

  dim3 g1(391, 2);
  k_gemm1f<<<g1, 256, 0, stream>>>(x, WT1h, N_NODES, S1h, h, br1);

  k_spmm1_csr<<<(N_NODES + 3) / 4, 256, 0, stream>>>(offs, es, S1h, b1, h);

  k_gemm2<<<391, 256, 0, stream>>>(h, WT2, N_NODES, S2h, oacc, b2, br2);

  k_spmm2_lsm<<<(N_NODES + 3) / 4, 256, 0, stream>>>(offs, es, S2h, oacc, out);
}

// Round 12
// 315.951 us; speedup vs baseline: 1.0537x; 1.0537x over previous
//
#include <hip/hip_runtime.h>
#include <stdint.h>

#define N_NODES 50000
#define N_EDGES 800000
#define NFEAT 512
#define NHID 128
#define NCLASS 40
#define NBLK 3125   // 800000 / 256 edge blocks
#define NBUCK 196   // ceil(50000/256) coarse dst buckets

typedef __attribute__((ext_vector_type(8))) __bf16 bf16x8;
typedef __attribute__((ext_vector_type(4))) float f32x4;
typedef _Float16 h2 __attribute__((ext_vector_type(2)));
typedef _Float16 f16x8 __attribute__((ext_vector_type(8)));

__device__ __forceinline__ uint16_t f2b(float f) {
  uint32_t x = __float_as_uint(f);
  uint32_t r = (x + 0x7fffu + ((x >> 16) & 1u)) >> 16;
  return (uint16_t)r;
}
__device__ __forceinline__ uint16_t f2h_bits(float f) {
  return __builtin_bit_cast(uint16_t, (_Float16)f);
}
__device__ __forceinline__ h2 cvt_pk(float a, float b) {
  return __builtin_bit_cast(h2, __builtin_amdgcn_cvt_pkrtz(a, b));
}

// ---------------- merged prologue: prep WT1(f16)/WT2(bf16) | p1 coarse hist (R11-proven) ----------------
__global__ void k_pre3(const float* __restrict__ W1, const float* __restrict__ Wr1,
                       const float* __restrict__ W2, const float* __restrict__ Wr2,
                       uint16_t* __restrict__ WT1h, uint16_t* __restrict__ WT2,
                       const int* __restrict__ dst, int* __restrict__ bc) {
  int b = blockIdx.x, t = threadIdx.x;
  if (b < 512) {
    int idx = b * 256 + t;  // 131072
    int n = idx >> 9, k = idx & 511;
    float v = (n < 128) ? W1[(size_t)k * 128 + n] : Wr1[(size_t)k * 128 + (n - 128)];
    WT1h[idx] = f2h_bits(v);
  } else if (b < 640) {
    int j = (b - 512) * 256 + t;  // 32768
    int n = j >> 8, k = j & 255;
    float v = 0.f;
    if (n < 40) v = W2[(size_t)k * 40 + n];
    else if (n < 80) v = Wr2[(size_t)k * 40 + (n - 40)];
    WT2[j] = f2b(v);
  } else {
    __shared__ int hist[NBUCK];
    int eb = b - 640;  // 0..3124
    if (t < NBUCK) hist[t] = 0;
    __syncthreads();
    int d = dst[eb * 256 + t];
    atomicAdd(&hist[d >> 8], 1);
    __syncthreads();
    if (t < NBUCK) bc[eb * NBUCK + t] = hist[t];
  }
}

// ---------------- P2: per-bucket scan over blocks (proven) ----------------
__global__ void k_p2(const int* __restrict__ bc, int* __restrict__ bc2,
                     int* __restrict__ bucketTotal) {
  __shared__ int part[256];
  int k = blockIdx.x, t = threadIdx.x;
  int vals[13];
  int s = 0;
  int base = t * 13;
#pragma unroll
  for (int i = 0; i < 13; i++) {
    int idx = base + i;
    int v = (idx < NBLK) ? bc[idx * NBUCK + k] : 0;
    vals[i] = v;
    s += v;
  }
  part[t] = s;
  __syncthreads();
  for (int o = 1; o < 256; o <<= 1) {
    int v = (t >= o) ? part[t - o] : 0;
    __syncthreads();
    part[t] += v;
    __syncthreads();
  }
  int run = (t == 0) ? 0 : part[t - 1];
#pragma unroll
  for (int i = 0; i < 13; i++) {
    int idx = base + i;
    if (idx < NBLK) {
      bc2[k * NBLK + idx] = run;
      run += vals[i];
    }
  }
  if (t == 255) bucketTotal[k] = part[255];
}

// ---------------- P4: coarse scatter, inline bucket-base scan, LDS cursors (proven) ----------------
__global__ void k_p4(const int* __restrict__ src, const int* __restrict__ dst,
                     const float* __restrict__ val, const int* __restrict__ bc2,
                     const int* __restrict__ bucketTotal, int2* __restrict__ esc) {
  __shared__ int sc[256];
  __shared__ int start[NBUCK];
  __shared__ int cur[NBUCK];
  int b = blockIdx.x, t = threadIdx.x;
  sc[t] = (t < NBUCK) ? bucketTotal[t] : 0;
  __syncthreads();
  for (int o = 1; o < 256; o <<= 1) {
    int v = (t >= o) ? sc[t - o] : 0;
    __syncthreads();
    sc[t] += v;
    __syncthreads();
  }
  if (t < NBUCK) {
    start[t] = ((t == 0) ? 0 : sc[t - 1]) + bc2[t * NBLK + b];
    cur[t] = 0;
  }
  __syncthreads();
  int e = b * 256 + t;
  int d = dst[e];
  int k = d >> 8;
  int r = atomicAdd(&cur[k], 1);  // LDS atomic
  esc[start[k] + r] = make_int2(src[e] | ((d & 255) << 16), __float_as_int(val[e]));
}

// ---------------- P5: per-bucket exact sort (proven) ----------------
__global__ void k_p5(const int2* __restrict__ esc, const int* __restrict__ bucketTotal,
                     int2* __restrict__ es, int* __restrict__ offs) {
  __shared__ int bsc[256];
  __shared__ int hist[256];
  __shared__ int sc[256];
  __shared__ int cur[256];
  int k = blockIdx.x, t = threadIdx.x;
  bsc[t] = (t < NBUCK) ? bucketTotal[t] : 0;
  __syncthreads();
  for (int o = 1; o < 256; o <<= 1) {
    int v = (t >= o) ? bsc[t - o] : 0;
    __syncthreads();
    bsc[t] += v;
    __syncthreads();
  }
  int base = (k == 0) ? 0 : bsc[k - 1];
  int n = bsc[k] - base;
  hist[t] = 0;
  __syncthreads();
  for (int i = t; i < n; i += 256) atomicAdd(&hist[esc[base + i].x >> 16], 1);
  __syncthreads();
  sc[t] = hist[t];
  __syncthreads();
  for (int o = 1; o < 256; o <<= 1) {
    int v = (t >= o) ? sc[t - o] : 0;
    __syncthreads();
    sc[t] += v;
    __syncthreads();
  }
  int excl = (t == 0) ? 0 : sc[t - 1];
  int node = k * 256 + t;
  if (node <= N_NODES) offs[node] = base + excl;
  cur[t] = excl;
  __syncthreads();
  for (int i = t; i < n; i += 256) {
    int2 e = esc[base + i];
    int l = e.x >> 16;
    int r = atomicAdd(&cur[l], 1);  // LDS atomic
    es[base + r] = make_int2(e.x & 0xFFFF, e.y);
  }
}

// ---------------- fused cast+GEMM1 v3: fp32 A staged via global_load_lds, f16 MFMA ----------------
// A: 128x64 fp32 (32 KB LDS) DMA-staged exactly like proven kernels (wave-uniform base + lane*16).
// cvt_pkrtz at fragment-read time. B: byte-identical proven f16 path. Same 2-barrier structure.
__global__ __launch_bounds__(256, 2) void k_gemm1x(
    const float* __restrict__ x, const uint16_t* __restrict__ BTh, int M,
    _Float16* __restrict__ S1h, uint16_t* __restrict__ h, const float* __restrict__ br1) {
  __shared__ float Af[128 * 64];      // 32 KB
  __shared__ uint16_t Bl[128 * 64];   // 16 KB
  const int tid = threadIdx.x;
  const int w = tid >> 6, lane = tid & 63;
  const int wm = w >> 1, wn = w & 1;
  const int m0 = blockIdx.x * 128;
  const int n0 = blockIdx.y * 128;

  f32x4 acc[4][4];
#pragma unroll
  for (int t = 0; t < 4; t++)
#pragma unroll
    for (int u = 0; u < 4; u++) acc[t][u] = (f32x4)0.f;

  const int lrow_b = lane >> 3;   // B: 8 rows/instr (128B rows)
  const int lcol_b = lane & 7;
  const int lrow_a = lane >> 4;   // A: 4 rows/instr (256B rows)
  const int lcol_a = lane & 15;   // 16B slot

  for (int kb = 0; kb < 8; ++kb) {
    __syncthreads();
    const int k0 = kb * 64;
    // B: 128x64 f16, 4 instrs/warp (proven pattern)
#pragma unroll
    for (int i = 0; i < 4; i++) {
      int rr = (w * 4 + i) * 8 + lrow_b;
      const uint16_t* gB = BTh + (size_t)(n0 + rr) * NFEAT + k0 + lcol_b * 8;
      __builtin_amdgcn_global_load_lds(
          (const __attribute__((address_space(1))) void*)gB,
          (__attribute__((address_space(3))) void*)&Bl[(w * 4 + i) * 512], 16, 0, 0);
    }
    // A: 128x64 fp32, 8 instrs/warp, 4 rows each (row stride 64 floats, contiguous lane order)
#pragma unroll
    for (int i = 0; i < 8; i++) {
      int rr = (w * 8 + i) * 4 + lrow_a;
      int ra = m0 + rr;
      if (ra >= M) ra = M - 1;  // clamp tail (stores guarded)
      const float* gA = x + (size_t)ra * NFEAT + k0 + lcol_a * 4;
      __builtin_amdgcn_global_load_lds(
          (const __attribute__((address_space(1))) void*)gA,
          (__attribute__((address_space(3))) void*)&Af[(w * 8 + i) * 256], 16, 0, 0);
    }
    __syncthreads();  // drains all DMA (compiler emits vmcnt(0))
#pragma unroll
    for (int s = 0; s < 2; s++) {
      f16x8 av[4], bv[4];
#pragma unroll
      for (int t = 0; t < 4; t++) {
        const float* p = &Af[(wm * 64 + t * 16 + (lane & 15)) * 64 + s * 32 + (lane >> 4) * 8];
        float4 f0 = *(const float4*)p;
        float4 f1 = *(const float4*)(p + 4);
        union { h2 hh[4]; f16x8 v; } u;
        u.hh[0] = cvt_pk(f0.x, f0.y);
        u.hh[1] = cvt_pk(f0.z, f0.w);
        u.hh[2] = cvt_pk(f1.x, f1.y);
        u.hh[3] = cvt_pk(f1.z, f1.w);
        av[t] = u.v;
      }
#pragma unroll
      for (int u4 = 0; u4 < 4; u4++)
        bv[u4] = *(const f16x8*)&Bl[(wn * 64 + u4 * 16 + (lane & 15)) * 64 + s * 32 + (lane >> 4) * 8];
#pragma unroll
      for (int t = 0; t < 4; t++)
#pragma unroll
        for (int u4 = 0; u4 < 4; u4++)
          acc[t][u4] = __builtin_amdgcn_mfma_f32_16x16x32_f16(av[t], bv[u4], acc[t][u4], 0, 0, 0);
    }
  }

  const int cl = lane & 15, rq = lane >> 4;
#pragma unroll
  for (int t = 0; t < 4; t++) {
#pragma unroll
    for (int u = 0; u < 4; u++) {
#pragma unroll
      for (int r = 0; r < 4; r++) {
        int m = m0 + wm * 64 + t * 16 + rq * 4 + r;
        int n = n0 + wn * 64 + u * 16 + cl;
        if (m >= M) continue;
        float v = acc[t][u][r];
        if (n < 128)
          S1h[(size_t)m * 128 + n] = (_Float16)v;  // x@W1 (b1 added post-spmm)
        else
          h[(size_t)m * 256 + n] = f2b(v + br1[n - 128]);  // h right = x@Wr1+br1
      }
    }
  }
}

// ---------------- GEMM2: h(bf16) @ WT2^T, 128x128 tile, f16 S2 + padded epilogue (proven) ----------------
__global__ __launch_bounds__(256, 2) void k_gemm2(
    const uint16_t* __restrict__ A, const uint16_t* __restrict__ BT, int M,
    _Float16* __restrict__ S2h, float* __restrict__ oacc,
    const float* __restrict__ b2, const float* __restrict__ br2) {
  __shared__ uint16_t Al[128 * 64];
  __shared__ uint16_t Bl[128 * 64];
  const int tid = threadIdx.x;
  const int w = tid >> 6, lane = tid & 63;
  const int wm = w >> 1, wn = w & 1;
  const int m0 = blockIdx.x * 128;
  const int K = 256;

  f32x4 acc[4][4];
#pragma unroll
  for (int t = 0; t < 4; t++)
#pragma unroll
    for (int u = 0; u < 4; u++) acc[t][u] = (f32x4)0.f;

  const int lrow = lane >> 3;
  const int lcol = lane & 7;

  for (int kb = 0; kb < K / 64; ++kb) {
    __syncthreads();
    const int k0 = kb * 64;
#pragma unroll
    for (int i = 0; i < 4; i++) {
      int rr = (w * 4 + i) * 8 + lrow;
      int ra = m0 + rr;
      if (ra >= M) ra = M - 1;
      const uint16_t* gA = A + (size_t)ra * K + k0 + lcol * 8;
      __builtin_amdgcn_global_load_lds(
          (const __attribute__((address_space(1))) void*)gA,
          (__attribute__((address_space(3))) void*)&Al[(w * 4 + i) * 512], 16, 0, 0);
      const uint16_t* gB = BT + (size_t)rr * K + k0 + lcol * 8;
      __builtin_amdgcn_global_load_lds(
          (const __attribute__((address_space(1))) void*)gB,
          (__attribute__((address_space(3))) void*)&Bl[(w * 4 + i) * 512], 16, 0, 0);
    }
    __syncthreads();
#pragma unroll
    for (int s = 0; s < 2; s++) {
      bf16x8 av[4], bv[4];
#pragma unroll
      for (int t = 0; t < 4; t++)
        av[t] = *(const bf16x8*)&Al[(wm * 64 + t * 16 + (lane & 15)) * 64 + s * 32 + (lane >> 4) * 8];
#pragma unroll
      for (int u = 0; u < 4; u++)
        bv[u] = *(const bf16x8*)&Bl[(wn * 64 + u * 16 + (lane & 15)) * 64 + s * 32 + (lane >> 4) * 8];
#pragma unroll
      for (int t = 0; t < 4; t++)
#pragma unroll
        for (int u = 0; u < 4; u++)
          acc[t][u] = __builtin_amdgcn_mfma_f32_16x16x32_bf16(av[t], bv[u], acc[t][u], 0, 0, 0);
    }
  }

  const int cl = lane & 15, rq = lane >> 4;
#pragma unroll
  for (int t = 0; t < 4; t++) {
#pragma unroll
    for (int u = 0; u < 4; u++) {
#pragma unroll
      for (int r = 0; r < 4; r++) {
        int m = m0 + wm * 64 + t * 16 + rq * 4 + r;
        int n = wn * 64 + u * 16 + cl;
        if (m >= M) continue;
        float v = acc[t][u][r];
        if (n < 40) S2h[(size_t)m * 64 + n] = (_Float16)v;
        else if (n < 64) S2h[(size_t)m * 64 + n] = (_Float16)0.f;
        if (n >= 40 && n < 80) oacc[(size_t)m * 64 + (n - 40)] = v + b2[n - 40] + br2[n - 40];
        else if (n >= 80 && n < 104) oacc[(size_t)m * 64 + (n - 40)] = 0.f;
      }
    }
  }
}

// ---------------- SpMM1 via CSR: wave/node, 8 edges/iter, f16 packed (proven) ----------------
__global__ void k_spmm1_csr(const int* __restrict__ offs, const int2* __restrict__ es,
                            const _Float16* __restrict__ S1h, const float* __restrict__ b1,
                            uint16_t* __restrict__ h) {
  int node = blockIdx.x * 4 + (threadIdx.x >> 6);
  if (node >= N_NODES) return;
  int lane = threadIdx.x & 63;
  int eg = lane >> 4;  // 0..3 edge slot
  int fg = lane & 15;  // 0..15 feat group (8 feats)
  int beg = offs[node], end = offs[node + 1];
  h2 acc[4];
#pragma unroll
  for (int j = 0; j < 4; j++) acc[j] = (h2)(_Float16)0.f;
  for (int p = beg; p < end; p += 8) {
    int pa = p + eg, pb = p + 4 + eg;
    bool oka = pa < end, okb = pb < end;
    int2 ea = es[oka ? pa : beg];
    int2 eb = es[okb ? pb : beg];
    float va = oka ? __int_as_float(ea.y) : 0.f;
    float vb = okb ? __int_as_float(eb.y) : 0.f;
    _Float16 vah = (_Float16)va, vbh = (_Float16)vb;
    h2 vva = {vah, vah}, vvb = {vbh, vbh};
    uint4 ga = *(const uint4*)(S1h + (size_t)ea.x * 128 + fg * 8);
    uint4 gb = *(const uint4*)(S1h + (size_t)eb.x * 128 + fg * 8);
    h2* ha = (h2*)&ga;
    h2* hb = (h2*)&gb;
#pragma unroll
    for (int j = 0; j < 4; j++) {
      acc[j] = vva * ha[j] + acc[j];
      acc[j] = vvb * hb[j] + acc[j];
    }
  }
#pragma unroll
  for (int j = 0; j < 4; j++) {
    int b16 = __shfl_xor(__builtin_bit_cast(int, acc[j]), 16, 64);
    acc[j] = acc[j] + __builtin_bit_cast(h2, b16);
    int b32 = __shfl_xor(__builtin_bit_cast(int, acc[j]), 32, 64);
    acc[j] = acc[j] + __builtin_bit_cast(h2, b32);
  }
  if (eg == 0) {
    const float4* bp = (const float4*)(b1 + fg * 8);
    float4 ba = bp[0], bb = bp[1];
    float r0 = (float)acc[0][0] + ba.x, r1 = (float)acc[0][1] + ba.y;
    float r2 = (float)acc[1][0] + ba.z, r3 = (float)acc[1][1] + ba.w;
    float r4 = (float)acc[2][0] + bb.x, r5 = (float)acc[2][1] + bb.y;
    float r6 = (float)acc[3][0] + bb.z, r7 = (float)acc[3][1] + bb.w;
    union { uint16_t u[8]; uint4 v; } o;
    o.u[0] = f2b(r0 > 0.f ? r0 : 0.f); o.u[1] = f2b(r1 > 0.f ? r1 : 0.f);
    o.u[2] = f2b(r2 > 0.f ? r2 : 0.f); o.u[3] = f2b(r3 > 0.f ? r3 : 0.f);
    o.u[4] = f2b(r4 > 0.f ? r4 : 0.f); o.u[5] = f2b(r5 > 0.f ? r5 : 0.f);
    o.u[6] = f2b(r6 > 0.f ? r6 : 0.f); o.u[7] = f2b(r7 > 0.f ? r7 : 0.f);
    *(uint4*)(h + (size_t)node * 256 + fg * 8) = o.v;
  }
}

// ---------------- SpMM2 via CSR + log_softmax: wave/node, 16 edges/iter (proven) ----------------
__global__ void k_spmm2_lsm(const int* __restrict__ offs, const int2* __restrict__ es,
                            const _Float16* __restrict__ S2h, const float* __restrict__ oacc,
                            float* __restrict__ out) {
  int node = blockIdx.x * 4 + (threadIdx.x >> 6);
  if (node >= N_NODES) return;
  int lane = threadIdx.x & 63;
  int eg = lane >> 3;  // 0..7 edge slot
  int fg = lane & 7;   // 0..7 feat group (8 feats of 64-padded row)
  int beg = offs[node], end = offs[node + 1];
  h2 acc[4];
#pragma unroll
  for (int j = 0; j < 4; j++) acc[j] = (h2)(_Float16)0.f;
  for (int p = beg; p < end; p += 16) {
    int pa = p + eg, pb = p + 8 + eg;
    bool oka = pa < end, okb = pb < end;
    int2 ea = es[oka ? pa : beg];
    int2 eb = es[okb ? pb : beg];
    float va = oka ? __int_as_float(ea.y) : 0.f;
    float vb = okb ? __int_as_float(eb.y) : 0.f;
    _Float16 vah = (_Float16)va, vbh = (_Float16)vb;
    h2 vva = {vah, vah}, vvb = {vbh, vbh};
    uint4 ga = *(const uint4*)(S2h + (size_t)ea.x * 64 + fg * 8);
    uint4 gb = *(const uint4*)(S2h + (size_t)eb.x * 64 + fg * 8);
    h2* ha = (h2*)&ga;
    h2* hb = (h2*)&gb;
#pragma unroll
    for (int j = 0; j < 4; j++) {
      acc[j] = vva * ha[j] + acc[j];
      acc[j] = vvb * hb[j] + acc[j];
    }
  }
#pragma unroll
  for (int j = 0; j < 4; j++) {
    int b8 = __shfl_xor(__builtin_bit_cast(int, acc[j]), 8, 64);
    acc[j] = acc[j] + __builtin_bit_cast(h2, b8);
    int b16 = __shfl_xor(__builtin_bit_cast(int, acc[j]), 16, 64);
    acc[j] = acc[j] + __builtin_bit_cast(h2, b16);
    int b32 = __shfl_xor(__builtin_bit_cast(int, acc[j]), 32, 64);
    acc[j] = acc[j] + __builtin_bit_cast(h2, b32);
  }
  const float4* op = (const float4*)(oacc + (size_t)node * 64 + fg * 8);
  float4 o0 = op[0], o1 = op[1];
  float v0 = (float)acc[0][0] + o0.x, v1 = (float)acc[0][1] + o0.y;
  float v2 = (float)acc[1][0] + o0.z, v3 = (float)acc[1][1] + o0.w;
  float v4 = (float)acc[2][0] + o1.x, v5 = (float)acc[2][1] + o1.y;
  float v6 = (float)acc[3][0] + o1.z, v7 = (float)acc[3][1] + o1.w;
  bool valid = fg < 5;  // feats 0..39
  float m01 = v0 > v1 ? v0 : v1, m23 = v2 > v3 ? v2 : v3;
  float m45 = v4 > v5 ? v4 : v5, m67 = v6 > v7 ? v6 : v7;
  float ml = m01 > m23 ? m01 : m23;
  float mh = m45 > m67 ? m45 : m67;
  float mv = ml > mh ? ml : mh;
  mv = valid ? mv : -1e30f;
#pragma unroll
  for (int o = 1; o <= 4; o <<= 1) {
    float t = __shfl_xor(mv, o, 64);
    mv = mv > t ? mv : t;
  }
  float se = 0.f;
  if (valid)
    se = __expf(v0 - mv) + __expf(v1 - mv) + __expf(v2 - mv) + __expf(v3 - mv) +
         __expf(v4 - mv) + __expf(v5 - mv) + __expf(v6 - mv) + __expf(v7 - mv);
#pragma unroll
  for (int o = 1; o <= 4; o <<= 1) se += __shfl_xor(se, o, 64);
  if (eg == 0 && valid) {
    float ls = mv + __logf(se);
    float4 r0 = make_float4(v0 - ls, v1 - ls, v2 - ls, v3 - ls);
    float4 r1 = make_float4(v4 - ls, v5 - ls, v6 - ls, v7 - ls);
    float4* wp = (float4*)(out + (size_t)node * 40 + fg * 8);
    wp[0] = r0;
    wp[1] = r1;
  }
}

extern "C" void kernel_launch(void* const* d_in, const int* in_sizes, int n_in,
                              void* d_out, int out_size, void* d_ws, size_t ws_size,
                              hipStream_t stream) {
  const float* x = (const float*)d_in[0];
  const int* esrc = (const int*)d_in[1];
  const int* edst = (const int*)d_in[2];
  const float* eval = (const float*)d_in[3];
  const float* W1 = (const float*)d_in[4];
  const float* b1 = (const float*)d_in[5];
  const float* Wr1 = (const float*)d_in[6];
  const float* br1 = (const float*)d_in[7];
  const float* W2 = (const float*)d_in[8];
  const float* b2 = (const float*)d_in[9];
  const float* Wr2 = (const float*)d_in[10];
  const float* br2 = (const float*)d_in[11];
  float* out = (float*)d_out;

  char* ws = (char*)d_ws;
  _Float16* S1h  = (_Float16*)(ws);              // 12,800,000
  uint16_t* h    = (uint16_t*)(ws + 12800000);   // 25,600,000
  uint16_t* WT1h = (uint16_t*)(ws + 38400000);   //    262,144 (f16)
  uint16_t* WT2  = (uint16_t*)(ws + 38662144);   //     65,536 (bf16)
  _Float16* S2h  = (_Float16*)(ws + 38727680);   //  6,400,000 (64-padded)
  float*    oacc = (float*)(ws + 45127680);      // 12,800,000 (64-padded)
  int*      offs = (int*)(ws + 57927680);        //    200,016 (padded)
  int2*     es   = (int2*)(ws + 58127696);       //  6,400,000
  int2*     esc  = (int2*)(ws + 64527696);       //  6,400,000
  int*      bc   = (int*)(ws + 70927696);        //  2,450,000 ([block][bucket])
  int*      bc2  = (int*)(ws + 73377696);        //  2,450,000 ([bucket][block])
  int*      bucketTotal = (int*)(ws + 75827696); //        784  (total ~75.8 MB)

  k_pre3<<<3765, 256, 0, stream>>>(W1, Wr1, W2, Wr2, WT1h, WT2, edst, bc);
  k_p2<<<NBUCK, 256, 0, stream>>>(bc, bc2, bucketTotal);
  k_p4<<<NBLK, 256, 0, stream>>>(esrc, edst, eval, bc2, bucketTotal, esc);
  k_p5<<<NBUCK, 256, 0, stream>>>(esc, bucketTotal, es, offs);

  dim3 g1(391, 2);
  k_gemm1x<<<g1, 256, 0, stream>>>(x, WT1h, N_NODES, S1h, h, br1);

  k_spmm1_csr<<<(N_NODES + 3) / 4, 256, 0, stream>>>(offs, es, S1h, b1, h);

  k_gemm2<<<391, 256, 0, stream>>>(h, WT2, N_NODES, S2h, oacc, b2, br2);

  k_spmm2_lsm<<<(N_NODES + 3) / 4, 256, 0, stream>>>(offs, es, S2h, oacc, out);
}